// Round 14
// baseline (101.419 us; speedup 1.0000x reference)
//
#include <hip/hip_runtime.h>
#include <hip/hip_bf16.h>

// CapsuleLayer dynamic routing, MI355X. fp32 in/out.
// C=10, B=128, N=1152, IN=8, OUT=16, 3 routing iters.
//
// v12 (round 14): r13 + pre-packed bf16 W'. Attacks the traffic x latency
//   product the r10/r13 pair exposed (G=2: 377MB/16 waves/41.8us vs G=1:
//   755MB/32 waves/50us — neither at L2 ceiling, VALU 22%): keep G=1's
//   4-blocks/CU occupancy, halve W bytes AND cut per-pass vmem 10 -> 6.
//   Prep kernel packs W fp32 -> W'[c][n][ipair][q][8 bf16] (2.95 MB, ~3us):
//   one uint4 = 2 i-slices x o-quad, so the build needs 4 W-loads/pass,
//   each 16 fully-consumed 64B lines. W L2 traffic 755 -> ~425 MB.
//   Precision: W-bf16 rounding rides on the already-paid P-bf16 storage
//   (r13 absmax 0.0059 -> expect ~0.009 vs threshold 0.0172). X stays fp32.
//
// Structure (r13-proven): one block per (c,b), 1280 blocks, 512 thr (8 waves),
//   P in LDS bf16x2 (37.9 KB -> 4 blocks/CU, 32 waves/CU; register-P is
//   untenable: r5-r9 AGPR-hoist / scratch-demotion traps). Lane l: o-quad
//   q=l&3, rsub=l>>2; wave w covers rows [w*144,(w+1)*144) in 9 passes of 16.
//   iter-0 fused into the build (e=1 sums in fp32). Logit state eliminated:
//   logit = dot(accum-out, P) per iter. Unnormalized softmax (fp32-safe).

constexpr int C = 10, B = 128, N = 1152, IN = 8, OUT = 16;
constexpr int THREADS = 512;
constexpr int NW = THREADS / 64;          // 8 waves
constexpr int PASSES = N / (NW * 16);     // 9

__device__ __forceinline__ unsigned packbf(float a, float b) {
    __hip_bfloat162 h = __float22bfloat162_rn(float2{a, b});  // RNE
    return *(unsigned*)&h;
}
__device__ __forceinline__ float bflo(unsigned u) { return __uint_as_float(u << 16); }
__device__ __forceinline__ float bfhi(unsigned u) { return __uint_as_float(u & 0xffff0000u); }

// ---- prep: W[c,n,i,o] fp32 -> W' uint4[(c*N+n)*16 + ipair*4 + q] ----
// uint4 = { bf16x2(W[i][o0],W[i][o1]), bf16x2(W[i][o2],W[i][o3]),
//           bf16x2(W[i+1][o0],W[i+1][o1]), bf16x2(W[i+1][o2],W[i+1][o3]) }
// with i = 2*ipair, oK = q*4+K.
constexpr int WPK_TOTAL = C * N * 16;     // 184,320 uint4

__global__ __launch_bounds__(256)
void pack_w(const float* __restrict__ Wf, uint4* __restrict__ Wp) {
    const int tid = blockIdx.x * 256 + threadIdx.x;
    if (tid >= WPK_TOTAL) return;
    const int q = tid & 3;
    const int ipair = (tid >> 2) & 3;
    const int cn = tid >> 4;
    const float* src = Wf + ((size_t)cn * IN + 2 * ipair) * OUT + q * 4;
    const float4 wa = *(const float4*)src;          // i   row, o-quad
    const float4 wb = *(const float4*)(src + OUT);  // i+1 row, o-quad
    Wp[tid] = uint4{packbf(wa.x, wa.y), packbf(wa.z, wa.w),
                    packbf(wb.x, wb.y), packbf(wb.z, wb.w)};
}

// ---- main: build priors -> LDS, 3 routing iters ----
__global__ __launch_bounds__(THREADS)
void caps_route(const float* __restrict__ Xf, const uint4* __restrict__ Wp,
                float* __restrict__ Of) {
    __shared__ uint2 ldsP[PASSES * THREADS];   // P bf16x2, 36,864 B
    __shared__ float lds_s[NW][OUT];           // per-wave weighted sums
    __shared__ float lds_sum[NW];              // per-wave softmax denoms
    __shared__ float lds_out[OUT];             // squashed output (per iter)

    const int t = threadIdx.x;
    const int l = t & 63;
    const int wid = t >> 6;
    const int q = l & 3;        // o-quad: owns o = q*4 .. q*4+3
    const int rsub = l >> 2;    // row-sub within a pass (0..15)
    const int blk = blockIdx.x;
    const int c = blk >> 7;     // 128 consecutive blocks share c -> W'[c] in L2/L3
    const int b = blk & 127;

    // iter-0 fused accumulators (e=1): fp32 sums of this thread's priors
    float s0 = 0.f, s1 = 0.f, s2 = 0.f, s3 = 0.f;

    // ---- priors: P[n][o] = sum_i x[b,n,i] * W[c,n,i,o] (fp32 acc, bf16 store)
    #pragma unroll
    for (int p = 0; p < PASSES; ++p) {
        const int n = wid * (16 * PASSES) + p * 16 + rsub;
        const uint4* wr = Wp + ((size_t)(c * N + n) << 4);
        const float4* xr = (const float4*)(Xf + (size_t)(b * N + n) * IN);
        const float4 xa = xr[0], xc = xr[1];
        const float xs[8] = { xa.x, xa.y, xa.z, xa.w, xc.x, xc.y, xc.z, xc.w };
        float a0 = 0.f, a1 = 0.f, a2 = 0.f, a3 = 0.f;
        #pragma unroll
        for (int ip = 0; ip < 4; ++ip) {
            const uint4 u = wr[ip * 4 + q];    // 2 i-slices; 16 full lines/instr
            const float xA = xs[2 * ip], xB = xs[2 * ip + 1];
            a0 = fmaf(xA, bflo(u.x), a0);  a0 = fmaf(xB, bflo(u.z), a0);
            a1 = fmaf(xA, bfhi(u.x), a1);  a1 = fmaf(xB, bfhi(u.z), a1);
            a2 = fmaf(xA, bflo(u.y), a2);  a2 = fmaf(xB, bflo(u.w), a2);
            a3 = fmaf(xA, bfhi(u.y), a3);  a3 = fmaf(xB, bfhi(u.w), a3);
        }
        ldsP[p * THREADS + t] = uint2{packbf(a0, a1), packbf(a2, a3)};
        s0 += a0; s1 += a1; s2 += a2; s3 += a3;     // iter-0 (e=1) fusion
    }

    // accumulated output quad-slice (fp32); logit[p] == dot(oa_full16, P[p])
    float oa[4] = {0.f, 0.f, 0.f, 0.f};

    // ---- dynamic routing ----
    for (int it = 0; it < 3; ++it) {
        float ssum;
        if (it == 0) {
            ssum = (float)PASSES;       // e = 1 for all logits
            // s0..s3 already hold this thread's prior sums (fused above)
        } else {
            ssum = 0.f;
            s0 = s1 = s2 = s3 = 0.f;
            #pragma unroll
            for (int p = 0; p < PASSES; ++p) {
                const uint2 u = ldsP[p * THREADS + t];
                const float p0 = bflo(u.x), p1 = bfhi(u.x);
                const float p2 = bflo(u.y), p3 = bfhi(u.y);
                // logit = dot(out_accum, P[n,:]) via quad butterfly
                float d = oa[0] * p0;
                d = fmaf(oa[1], p1, d);
                d = fmaf(oa[2], p2, d);
                d = fmaf(oa[3], p3, d);
                d += __shfl_xor(d, 1, 64);
                d += __shfl_xor(d, 2, 64);
                const float e = __expf(d);          // replicated across quad
                ssum += e;
                s0 = fmaf(e, p0, s0);
                s1 = fmaf(e, p1, s1);
                s2 = fmaf(e, p2, s2);
                s3 = fmaf(e, p3, s3);
            }
        }
        // wave reduce across 16 row-subs (masks 4..32; quad bits hold
        // replicas (ssum) / distinct o (s0..s3))
        #pragma unroll
        for (int m = 4; m < 64; m <<= 1) {
            ssum += __shfl_xor(ssum, m, 64);
            s0 += __shfl_xor(s0, m, 64);
            s1 += __shfl_xor(s1, m, 64);
            s2 += __shfl_xor(s2, m, 64);
            s3 += __shfl_xor(s3, m, 64);
        }
        if (l < 4) {                    // lane l == quad q: owns o = l*4..l*4+3
            lds_s[wid][l * 4 + 0] = s0;
            lds_s[wid][l * 4 + 1] = s1;
            lds_s[wid][l * 4 + 2] = s2;
            lds_s[wid][l * 4 + 3] = s3;
        }
        if (l == 0) lds_sum[wid] = ssum;
        __syncthreads();   // A

        // cross-wave combine + squash on t<16
        if (t < OUT) {
            float so = 0.f, S = 0.f;
            #pragma unroll
            for (int w = 0; w < NW; ++w) { so += lds_s[w][t]; S += lds_sum[w]; }
            so /= S;                    // s_o = softmax-weighted prior sum
            float r = so * so;          // ||s||^2 via 16-lane butterfly
            r += __shfl_xor(r, 1, 64);
            r += __shfl_xor(r, 2, 64);
            r += __shfl_xor(r, 4, 64);
            r += __shfl_xor(r, 8, 64);
            const float ov = so * (r / ((1.f + r) * sqrtf(r + 1e-8f)));
            if (it == 2) Of[(size_t)blk * OUT + t] = ov;
            else         lds_out[t] = ov;
        }

        if (it < 2) {
            __syncthreads();   // B
            oa[0] += lds_out[q * 4 + 0];
            oa[1] += lds_out[q * 4 + 1];
            oa[2] += lds_out[q * 4 + 2];
            oa[3] += lds_out[q * 4 + 3];
        }
    }
}

extern "C" void kernel_launch(void* const* d_in, const int* in_sizes, int n_in,
                              void* d_out, int out_size, void* d_ws, size_t ws_size,
                              hipStream_t stream) {
    const float* X = (const float*)d_in[0];   // [B,N,IN] fp32
    const float* W = (const float*)d_in[1];   // [C,N,IN,OUT] fp32
    float* O = (float*)d_out;                 // [C,B,OUT] fp32
    uint4* Wp = (uint4*)d_ws;                 // packed bf16 W', 2.95 MB

    hipLaunchKernelGGL(pack_w, dim3((WPK_TOTAL + 255) / 256), dim3(256), 0, stream, W, Wp);
    hipLaunchKernelGGL(caps_route, dim3(C * B), dim3(THREADS), 0, stream, X, Wp, O);
}